// Round 1
// baseline (1478.626 us; speedup 1.0000x reference)
//
#include <hip/hip_runtime.h>
#include <math.h>

// Problem constants (B,C,H,W = 32,2048,24,24; MID=256)
static constexpr int B_   = 32;
static constexpr int C_   = 2048;
static constexpr int N_   = 576;   // H*W
static constexpr int MID_ = 256;
static constexpr int M_   = 512;   // 2*MID (W1 and W2 stacked)

// ---------------------------------------------------------------------------
// K1: f12[b, m, n] = sum_c Wcat[m, c] * feat[b, c, n]
//     Wcat = [W1; W2] (512 x 2048), feat[b] is (2048 x 576)
//     64x64 tile per block, 256 threads, 4x4 micro-tile, K-chunk 16.
// ---------------------------------------------------------------------------
__global__ __launch_bounds__(256) void k_f12(
    const float* __restrict__ feat, const float* __restrict__ W1,
    const float* __restrict__ W2, float* __restrict__ f12) {
  const int nt = blockIdx.x;  // 0..8
  const int mt = blockIdx.y;  // 0..7
  const int b  = blockIdx.z;
  __shared__ float As[16][68];  // [c][m]  (+4 pad: strided writes -> 2-way)
  __shared__ float Bs[16][68];  // [c][n]
  const float* feat_b = feat + (size_t)b * C_ * N_;
  const int t  = threadIdx.x;
  const int tm = (t >> 4) << 2;
  const int tn = (t & 15) << 2;
  float acc[4][4] = {};
  for (int k0 = 0; k0 < C_; k0 += 16) {
    {  // A tile: Wcat[mt*64 + ml][k0 + c]
      const int c = t & 15;
      const int m = t >> 4;  // 0..15
#pragma unroll
      for (int p = 0; p < 4; ++p) {
        const int ml = m + p * 16;
        const int mg = mt * 64 + ml;
        const float* Wsrc = (mg < MID_) ? (W1 + (size_t)mg * C_)
                                        : (W2 + (size_t)(mg - MID_) * C_);
        As[c][ml] = Wsrc[k0 + c];
      }
    }
    {  // B tile: feat_b[(k0+c)*N + nt*64 + n]  (coalesced)
      const int n  = t & 63;
      const int c4 = t >> 6;  // 0..3
#pragma unroll
      for (int q = 0; q < 4; ++q) {
        const int c = c4 * 4 + q;
        Bs[c][n] = feat_b[(size_t)(k0 + c) * N_ + nt * 64 + n];
      }
    }
    __syncthreads();
#pragma unroll
    for (int k = 0; k < 16; ++k) {
      const float4 a4 = *(const float4*)&As[k][tm];
      const float4 b4 = *(const float4*)&Bs[k][tn];
      const float a[4]  = {a4.x, a4.y, a4.z, a4.w};
      const float bb[4] = {b4.x, b4.y, b4.z, b4.w};
#pragma unroll
      for (int i = 0; i < 4; ++i)
#pragma unroll
        for (int j = 0; j < 4; ++j) acc[i][j] += a[i] * bb[j];
    }
    __syncthreads();
  }
  float* out_b = f12 + (size_t)b * M_ * N_;
#pragma unroll
  for (int i = 0; i < 4; ++i) {
    float4 v = {acc[i][0], acc[i][1], acc[i][2], acc[i][3]};
    *(float4*)&out_b[(size_t)(mt * 64 + tm + i) * N_ + nt * 64 + tn] = v;
  }
}

// ---------------------------------------------------------------------------
// K2: attn[b, i, j] = sum_m f1[b, m, i] * f2[b, m, j]   (m = 0..255)
//     f1 = f12[b, 0:256, :], f2 = f12[b, 256:512, :]
// ---------------------------------------------------------------------------
__global__ __launch_bounds__(256) void k_logits(
    const float* __restrict__ f12, float* __restrict__ attn) {
  const int jt = blockIdx.x;  // 0..8
  const int it = blockIdx.y;  // 0..8
  const int b  = blockIdx.z;
  __shared__ float As[16][68];  // [m][i]
  __shared__ float Bs[16][68];  // [m][j]
  const float* f1 = f12 + (size_t)b * M_ * N_;
  const float* f2 = f1 + (size_t)MID_ * N_;
  const int t  = threadIdx.x;
  const int ti = (t >> 4) << 2;
  const int tj = (t & 15) << 2;
  float acc[4][4] = {};
  for (int k0 = 0; k0 < MID_; k0 += 16) {
    const int x  = t & 63;
    const int k4 = t >> 6;
#pragma unroll
    for (int q = 0; q < 4; ++q) {
      const int k = k4 * 4 + q;
      As[k][x] = f1[(size_t)(k0 + k) * N_ + it * 64 + x];
      Bs[k][x] = f2[(size_t)(k0 + k) * N_ + jt * 64 + x];
    }
    __syncthreads();
#pragma unroll
    for (int k = 0; k < 16; ++k) {
      const float4 a4 = *(const float4*)&As[k][ti];
      const float4 b4 = *(const float4*)&Bs[k][tj];
      const float a[4]  = {a4.x, a4.y, a4.z, a4.w};
      const float bb[4] = {b4.x, b4.y, b4.z, b4.w};
#pragma unroll
      for (int i = 0; i < 4; ++i)
#pragma unroll
        for (int j = 0; j < 4; ++j) acc[i][j] += a[i] * bb[j];
    }
    __syncthreads();
  }
  float* attn_b = attn + (size_t)b * N_ * N_;
#pragma unroll
  for (int i = 0; i < 4; ++i) {
    float4 v = {acc[i][0], acc[i][1], acc[i][2], acc[i][3]};
    *(float4*)&attn_b[(size_t)(it * 64 + ti + i) * N_ + jt * 64 + tj] = v;
  }
}

// ---------------------------------------------------------------------------
// K3: row softmax over j (576 elems) — one wave (64 lanes) per row, in-place.
// ---------------------------------------------------------------------------
__global__ __launch_bounds__(64) void k_softmax(float* __restrict__ attn) {
  const int row = blockIdx.x;  // b*576 + i
  float* p = attn + (size_t)row * N_;
  const int lane = threadIdx.x;
  float v[9];
  float mx = -INFINITY;
#pragma unroll
  for (int q = 0; q < 9; ++q) {
    v[q] = p[lane + q * 64];
    mx = fmaxf(mx, v[q]);
  }
#pragma unroll
  for (int off = 32; off > 0; off >>= 1) mx = fmaxf(mx, __shfl_down(mx, off));
  mx = __shfl(mx, 0);
  float s = 0.f;
#pragma unroll
  for (int q = 0; q < 9; ++q) {
    v[q] = __expf(v[q] - mx);
    s += v[q];
  }
#pragma unroll
  for (int off = 32; off > 0; off >>= 1) s += __shfl_down(s, off);
  s = __shfl(s, 0);
  const float inv = 1.0f / s;
#pragma unroll
  for (int q = 0; q < 9; ++q) p[lane + q * 64] = v[q] * inv;
}

// ---------------------------------------------------------------------------
// K4: out[b, c, i] = alpha * sum_j attn[b, i, j] * cam[b, c, j] + cam[b, c, i]
//     GEMM: M=2048 (c), N=576 (i), K=576 (j); both operands K-contiguous.
// ---------------------------------------------------------------------------
__global__ __launch_bounds__(256) void k_out(
    const float* __restrict__ cam, const float* __restrict__ attn,
    const float* __restrict__ alpha_p, float* __restrict__ out) {
  const int it = blockIdx.x;  // 0..8   (i tiles)
  const int ct = blockIdx.y;  // 0..31  (c tiles)
  const int b  = blockIdx.z;
  __shared__ float As[16][68];  // [j][c]
  __shared__ float Bs[16][68];  // [j][i]
  const float* cam_b  = cam + (size_t)b * C_ * N_;
  const float* attn_b = attn + (size_t)b * N_ * N_;
  const int t  = threadIdx.x;
  const int tc = (t >> 4) << 2;
  const int ti = (t & 15) << 2;
  float acc[4][4] = {};
  for (int k0 = 0; k0 < N_; k0 += 16) {
    const int kq = t & 15;
    const int r  = t >> 4;  // 0..15
#pragma unroll
    for (int p = 0; p < 4; ++p) {
      const int rl = r + p * 16;
      As[kq][rl] = cam_b[(size_t)(ct * 64 + rl) * N_ + k0 + kq];
      Bs[kq][rl] = attn_b[(size_t)(it * 64 + rl) * N_ + k0 + kq];
    }
    __syncthreads();
#pragma unroll
    for (int k = 0; k < 16; ++k) {
      const float4 a4 = *(const float4*)&As[k][tc];
      const float4 b4 = *(const float4*)&Bs[k][ti];
      const float a[4]  = {a4.x, a4.y, a4.z, a4.w};
      const float bb[4] = {b4.x, b4.y, b4.z, b4.w};
#pragma unroll
      for (int i = 0; i < 4; ++i)
#pragma unroll
        for (int j = 0; j < 4; ++j) acc[i][j] += a[i] * bb[j];
    }
    __syncthreads();
  }
  const float alpha = *alpha_p;
  float* out_b = out + (size_t)b * C_ * N_;
#pragma unroll
  for (int i = 0; i < 4; ++i) {
    const size_t row = (size_t)(ct * 64 + tc + i) * N_;
    const int col = it * 64 + ti;
    const float4 cv = *(const float4*)&cam_b[row + col];
    float4 v;
    v.x = alpha * acc[i][0] + cv.x;
    v.y = alpha * acc[i][1] + cv.y;
    v.z = alpha * acc[i][2] + cv.z;
    v.w = alpha * acc[i][3] + cv.w;
    *(float4*)&out_b[row + col] = v;
  }
}

// ---------------------------------------------------------------------------
extern "C" void kernel_launch(void* const* d_in, const int* in_sizes, int n_in,
                              void* d_out, int out_size, void* d_ws,
                              size_t ws_size, hipStream_t stream) {
  const float* cam   = (const float*)d_in[0];
  const float* feat  = (const float*)d_in[1];
  const float* W1    = (const float*)d_in[2];
  const float* W2    = (const float*)d_in[3];
  const float* alpha = (const float*)d_in[4];
  float* out = (float*)d_out;

  // workspace: f12 (32*512*576 fp32 = 37.75 MB) then attn (32*576*576 = 42.5 MB)
  float* f12  = (float*)d_ws;
  float* attn = f12 + (size_t)B_ * M_ * N_;

  k_f12<<<dim3(9, 8, B_), 256, 0, stream>>>(feat, W1, W2, f12);
  k_logits<<<dim3(9, 9, B_), 256, 0, stream>>>(f12, attn);
  k_softmax<<<dim3(B_ * N_), 64, 0, stream>>>(attn);
  k_out<<<dim3(9, 32, B_), 256, 0, stream>>>(cam, attn, alpha, out);
}

// Round 2
// 741.574 us; speedup vs baseline: 1.9939x; 1.9939x over previous
//
#include <hip/hip_runtime.h>
#include <math.h>

typedef unsigned short u16;
typedef unsigned int u32;
typedef __attribute__((ext_vector_type(8))) short short8;    // bf16x8 MFMA frag
typedef __attribute__((ext_vector_type(8))) unsigned short u16x8;
typedef __attribute__((ext_vector_type(4))) float f32x4;     // MFMA acc

static constexpr int B_   = 32;
static constexpr int C_   = 2048;
static constexpr int N_   = 576;   // H*W
static constexpr int MID_ = 256;
static constexpr int M_   = 512;   // 2*MID

__device__ __forceinline__ u16 bf16_rne(float x) {
  u32 u = __float_as_uint(x);
  return (u16)((u + 0x7FFFu + ((u >> 16) & 1u)) >> 16);
}
__device__ __forceinline__ float bf16f(u16 h) {
  return __uint_as_float(((u32)h) << 16);
}

// ---------------------------------------------------------------------------
// Prep: Wcat = [W1;W2] (512x2048) -> split bf16 hi/lo arrays (k-contiguous).
// ---------------------------------------------------------------------------
__global__ __launch_bounds__(256) void k_prep_w(
    const float* __restrict__ W1, const float* __restrict__ W2,
    u16* __restrict__ Wh, u16* __restrict__ Wl) {
  const int idx = blockIdx.x * 256 + threadIdx.x;  // x4 elems each
  const int e0 = idx * 4;
  const int m = e0 >> 11;
  const int c = e0 & 2047;
  const float* src = (m < MID_) ? &W1[(size_t)m * C_ + c]
                                : &W2[(size_t)(m - MID_) * C_ + c];
  const float4 v = *(const float4*)src;
  const float f[4] = {v.x, v.y, v.z, v.w};
  u16 h[4], l[4];
#pragma unroll
  for (int i = 0; i < 4; ++i) {
    h[i] = bf16_rne(f[i]);
    l[i] = bf16_rne(f[i] - bf16f(h[i]));
  }
  *(ushort4*)&Wh[e0] = make_ushort4(h[0], h[1], h[2], h[3]);
  *(ushort4*)&Wl[e0] = make_ushort4(l[0], l[1], l[2], l[3]);
}

// ---------------------------------------------------------------------------
// K1: f12t[b][n][m] = sum_c feat[b][c][n] * Wcat[m][c]   (packed hi|lo u32)
// MFMA: M-dim=n (A=feat, transposed+split during staging), N-dim=m (B=Wcat),
// K=c. 128x128 tile, BK=32, 3-term split MFMA.
// ---------------------------------------------------------------------------
__global__ __launch_bounds__(256) void k_f12(
    const float* __restrict__ feat, const u16* __restrict__ Wh,
    const u16* __restrict__ Wl, u32* __restrict__ f12p) {
  const int mt = blockIdx.x;  // 0..3   (m tiles)
  const int nt = blockIdx.y;  // 0..4   (n tiles)
  const int b  = blockIdx.z;
  __shared__ __align__(16) u16 Ah[128 * 40], Al[128 * 40];
  __shared__ __align__(16) u16 Bh[128 * 40], Bl[128 * 40];
  const float* feat_b = feat + (size_t)b * C_ * N_;
  const int t = threadIdx.x;
  const int lane = t & 63;
  const int wave = t >> 6;
  const int wm = (wave >> 1) * 64;  // n-dim offset within tile
  const int wn = (wave & 1) * 64;   // m-dim offset within tile
  const int n0 = nt * 128;
  const int m0 = mt * 128;
  // staging coords
  const int a_cq = t & 7;    // c = 4*a_cq + e
  const int a_n4 = t >> 3;   // n = 4*a_n4 + j  (0..31)
  const int b_m  = t >> 1;   // W row within tile
  const int b_h  = t & 1;    // k half
  const int nld = min(n0 + 4 * a_n4, N_ - 4);  // clamped float4 base (n)

  f32x4 acc[4][4];
#pragma unroll
  for (int i = 0; i < 4; ++i)
#pragma unroll
    for (int j = 0; j < 4; ++j) acc[i][j] = (f32x4)(0.0f);

  for (int k0 = 0; k0 < C_; k0 += 32) {
    // --- A: feat [c][n] fp32 -> LDS [n][c] split hi/lo (on-the-fly transpose)
    float va[4][4];  // [e(c)][j(n)]
#pragma unroll
    for (int e = 0; e < 4; ++e) {
      const float4 v = *(const float4*)&feat_b[(size_t)(k0 + 4 * a_cq + e) * N_ + nld];
      va[e][0] = v.x; va[e][1] = v.y; va[e][2] = v.z; va[e][3] = v.w;
    }
#pragma unroll
    for (int j = 0; j < 4; ++j) {
      u16 h[4], l[4];
#pragma unroll
      for (int e = 0; e < 4; ++e) {
        const float x = va[e][j];
        h[e] = bf16_rne(x);
        l[e] = bf16_rne(x - bf16f(h[e]));
      }
      const int row = 4 * a_n4 + j;
      uint2 hv, lv;
      hv.x = (u32)h[0] | ((u32)h[1] << 16); hv.y = (u32)h[2] | ((u32)h[3] << 16);
      lv.x = (u32)l[0] | ((u32)l[1] << 16); lv.y = (u32)l[2] | ((u32)l[3] << 16);
      *(uint2*)&Ah[row * 40 + 4 * a_cq] = hv;
      *(uint2*)&Al[row * 40 + 4 * a_cq] = lv;
    }
    // --- B: Wh/Wl (pre-split, k-contiguous) -> LDS [m][k]
#pragma unroll
    for (int e = 0; e < 2; ++e) {
      const int koff = 16 * b_h + 8 * e;
      *(u16x8*)&Bh[b_m * 40 + koff] = *(const u16x8*)&Wh[(size_t)(m0 + b_m) * C_ + k0 + koff];
      *(u16x8*)&Bl[b_m * 40 + koff] = *(const u16x8*)&Wl[(size_t)(m0 + b_m) * C_ + k0 + koff];
    }
    __syncthreads();
    // --- frags + MFMA (3-term split)
    const int fr = lane & 15;
    const int q8 = (lane >> 4) * 8;
    short8 afh[4], afl[4], bfh[4], bfl[4];
#pragma unroll
    for (int i = 0; i < 4; ++i) {
      afh[i] = *(const short8*)&Ah[(wm + 16 * i + fr) * 40 + q8];
      afl[i] = *(const short8*)&Al[(wm + 16 * i + fr) * 40 + q8];
      bfh[i] = *(const short8*)&Bh[(wn + 16 * i + fr) * 40 + q8];
      bfl[i] = *(const short8*)&Bl[(wn + 16 * i + fr) * 40 + q8];
    }
#pragma unroll
    for (int i = 0; i < 4; ++i)
#pragma unroll
      for (int j = 0; j < 4; ++j) {
        acc[i][j] = __builtin_amdgcn_mfma_f32_16x16x32_bf16(afh[i], bfh[j], acc[i][j], 0, 0, 0);
        acc[i][j] = __builtin_amdgcn_mfma_f32_16x16x32_bf16(afh[i], bfl[j], acc[i][j], 0, 0, 0);
        acc[i][j] = __builtin_amdgcn_mfma_f32_16x16x32_bf16(afl[i], bfh[j], acc[i][j], 0, 0, 0);
      }
    __syncthreads();
  }
  // --- epilogue: split acc -> packed hi|lo u32 at f12p[b][n][m]
  u32* out_b = f12p + (size_t)b * N_ * M_;
#pragma unroll
  for (int i = 0; i < 4; ++i) {
    const int nbase = n0 + wm + 16 * i + ((lane >> 4) * 4);
#pragma unroll
    for (int j = 0; j < 4; ++j) {
      const int m = m0 + wn + 16 * j + (lane & 15);
#pragma unroll
      for (int r = 0; r < 4; ++r) {
        const int n = nbase + r;
        if (n < N_) {
          const float x = acc[i][j][r];
          const u16 hh = bf16_rne(x);
          const u16 ll = bf16_rne(x - bf16f(hh));
          out_b[(size_t)n * M_ + m] = (u32)hh | ((u32)ll << 16);
        }
      }
    }
  }
}

// ---------------------------------------------------------------------------
// K2: logits[b][i][j] = sum_m f1t[i][m] * f2t[j][m]  (m=0..255)
// A = f12p rows i (k = m in [0,256)), B = f12p rows j (k offset +256).
// 3-term split MFMA; unpack hi/lo from packed u32 during staging.
// ---------------------------------------------------------------------------
__device__ __forceinline__ void unpack8(const uint4 a, const uint4 b,
                                        u16x8& h, u16x8& l) {
  const u32 w[8] = {a.x, a.y, a.z, a.w, b.x, b.y, b.z, b.w};
#pragma unroll
  for (int i = 0; i < 8; ++i) {
    h[i] = (u16)(w[i] & 0xffffu);
    l[i] = (u16)(w[i] >> 16);
  }
}

__global__ __launch_bounds__(256) void k_logits(
    const u32* __restrict__ f12p, float* __restrict__ logits) {
  const int jt = blockIdx.x;  // 0..4
  const int it = blockIdx.y;  // 0..4
  const int b  = blockIdx.z;
  __shared__ __align__(16) u16 Ah[128 * 40], Al[128 * 40];
  __shared__ __align__(16) u16 Bh[128 * 40], Bl[128 * 40];
  const u32* f_b = f12p + (size_t)b * N_ * M_;
  const int t = threadIdx.x;
  const int lane = t & 63;
  const int wave = t >> 6;
  const int wm = (wave >> 1) * 64;  // i-dim
  const int wn = (wave & 1) * 64;   // j-dim
  const int i0 = it * 128, j0 = jt * 128;
  const int row  = t >> 1;
  const int half = t & 1;
  const int a_row = min(i0 + row, N_ - 1);
  const int b_row = min(j0 + row, N_ - 1);

  f32x4 acc[4][4];
#pragma unroll
  for (int i = 0; i < 4; ++i)
#pragma unroll
    for (int j = 0; j < 4; ++j) acc[i][j] = (f32x4)(0.0f);

  for (int k0 = 0; k0 < MID_; k0 += 32) {
    {
      const u32* src = f_b + (size_t)a_row * M_ + k0 + 16 * half;
      uint4 p0 = *(const uint4*)&src[0];
      uint4 p1 = *(const uint4*)&src[4];
      uint4 p2 = *(const uint4*)&src[8];
      uint4 p3 = *(const uint4*)&src[12];
      u16x8 h0, l0, h1, l1;
      unpack8(p0, p1, h0, l0);
      unpack8(p2, p3, h1, l1);
      *(u16x8*)&Ah[row * 40 + 16 * half + 0] = h0;
      *(u16x8*)&Ah[row * 40 + 16 * half + 8] = h1;
      *(u16x8*)&Al[row * 40 + 16 * half + 0] = l0;
      *(u16x8*)&Al[row * 40 + 16 * half + 8] = l1;
    }
    {
      const u32* src = f_b + (size_t)b_row * M_ + MID_ + k0 + 16 * half;
      uint4 p0 = *(const uint4*)&src[0];
      uint4 p1 = *(const uint4*)&src[4];
      uint4 p2 = *(const uint4*)&src[8];
      uint4 p3 = *(const uint4*)&src[12];
      u16x8 h0, l0, h1, l1;
      unpack8(p0, p1, h0, l0);
      unpack8(p2, p3, h1, l1);
      *(u16x8*)&Bh[row * 40 + 16 * half + 0] = h0;
      *(u16x8*)&Bh[row * 40 + 16 * half + 8] = h1;
      *(u16x8*)&Bl[row * 40 + 16 * half + 0] = l0;
      *(u16x8*)&Bl[row * 40 + 16 * half + 8] = l1;
    }
    __syncthreads();
    const int fr = lane & 15;
    const int q8 = (lane >> 4) * 8;
    short8 afh[4], afl[4], bfh[4], bfl[4];
#pragma unroll
    for (int i = 0; i < 4; ++i) {
      afh[i] = *(const short8*)&Ah[(wm + 16 * i + fr) * 40 + q8];
      afl[i] = *(const short8*)&Al[(wm + 16 * i + fr) * 40 + q8];
      bfh[i] = *(const short8*)&Bh[(wn + 16 * i + fr) * 40 + q8];
      bfl[i] = *(const short8*)&Bl[(wn + 16 * i + fr) * 40 + q8];
    }
#pragma unroll
    for (int i = 0; i < 4; ++i)
#pragma unroll
      for (int j = 0; j < 4; ++j) {
        acc[i][j] = __builtin_amdgcn_mfma_f32_16x16x32_bf16(afh[i], bfh[j], acc[i][j], 0, 0, 0);
        acc[i][j] = __builtin_amdgcn_mfma_f32_16x16x32_bf16(afh[i], bfl[j], acc[i][j], 0, 0, 0);
        acc[i][j] = __builtin_amdgcn_mfma_f32_16x16x32_bf16(afl[i], bfh[j], acc[i][j], 0, 0, 0);
      }
    __syncthreads();
  }
  float* log_b = logits + (size_t)b * N_ * N_;
#pragma unroll
  for (int i = 0; i < 4; ++i) {
    const int ibase = i0 + wm + 16 * i + ((lane >> 4) * 4);
#pragma unroll
    for (int j = 0; j < 4; ++j) {
      const int jj = j0 + wn + 16 * j + (lane & 15);
      if (jj < N_) {
#pragma unroll
        for (int r = 0; r < 4; ++r) {
          const int ii = ibase + r;
          if (ii < N_) log_b[(size_t)ii * N_ + jj] = acc[i][j][r];
        }
      }
    }
  }
}

// ---------------------------------------------------------------------------
// K3: row softmax (576) — one wave per row; fp32 in, bf16 out.
// ---------------------------------------------------------------------------
__global__ __launch_bounds__(64) void k_softmax(
    const float* __restrict__ logits, u16* __restrict__ attn) {
  const int row = blockIdx.x;  // b*576 + i
  const float* p = logits + (size_t)row * N_;
  u16* o = attn + (size_t)row * N_;
  const int lane = threadIdx.x;
  float v[9];
  float mx = -INFINITY;
#pragma unroll
  for (int q = 0; q < 9; ++q) {
    v[q] = p[lane + q * 64];
    mx = fmaxf(mx, v[q]);
  }
#pragma unroll
  for (int off = 32; off > 0; off >>= 1) mx = fmaxf(mx, __shfl_down(mx, off));
  mx = __shfl(mx, 0);
  float s = 0.f;
#pragma unroll
  for (int q = 0; q < 9; ++q) {
    v[q] = __expf(v[q] - mx);
    s += v[q];
  }
#pragma unroll
  for (int off = 32; off > 0; off >>= 1) s += __shfl_down(s, off);
  s = __shfl(s, 0);
  const float inv = 1.0f / s;
#pragma unroll
  for (int q = 0; q < 9; ++q) o[lane + q * 64] = bf16_rne(v[q] * inv);
}

// ---------------------------------------------------------------------------
// K4: out[b][c][i] = alpha * sum_j attn[b][i][j]*cam[b][c][j] + cam[b][c][i]
// MFMA: M=c (A=cam, bf16-cvt in staging), N=i (B=attn bf16), K=j.
// ---------------------------------------------------------------------------
__global__ __launch_bounds__(256) void k_out(
    const float* __restrict__ cam, const u16* __restrict__ attn,
    const float* __restrict__ alpha_p, float* __restrict__ out) {
  const int ct = blockIdx.x;  // 0..15
  const int it = blockIdx.y;  // 0..4
  const int b  = blockIdx.z;
  __shared__ __align__(16) u16 As[128 * 40], Bs[128 * 40];
  const float* cam_b = cam + (size_t)b * C_ * N_;
  const u16* attn_b = attn + (size_t)b * N_ * N_;
  const int t = threadIdx.x;
  const int lane = t & 63;
  const int wave = t >> 6;
  const int wm = (wave >> 1) * 64;  // c-dim
  const int wn = (wave & 1) * 64;   // i-dim
  const int row  = t >> 1;
  const int half = t & 1;
  const int c_ld = ct * 128 + row;
  const int i_ld = min(it * 128 + row, N_ - 1);

  f32x4 acc[4][4];
#pragma unroll
  for (int i = 0; i < 4; ++i)
#pragma unroll
    for (int j = 0; j < 4; ++j) acc[i][j] = (f32x4)(0.0f);

  for (int k0 = 0; k0 < N_; k0 += 32) {
#pragma unroll
    for (int e = 0; e < 2; ++e) {
      const int koff = 16 * half + 8 * e;
      const float4 v0 = *(const float4*)&cam_b[(size_t)c_ld * N_ + k0 + koff];
      const float4 v1 = *(const float4*)&cam_b[(size_t)c_ld * N_ + k0 + koff + 4];
      u16x8 hv;
      hv[0] = bf16_rne(v0.x); hv[1] = bf16_rne(v0.y);
      hv[2] = bf16_rne(v0.z); hv[3] = bf16_rne(v0.w);
      hv[4] = bf16_rne(v1.x); hv[5] = bf16_rne(v1.y);
      hv[6] = bf16_rne(v1.z); hv[7] = bf16_rne(v1.w);
      *(u16x8*)&As[row * 40 + koff] = hv;
      *(u16x8*)&Bs[row * 40 + koff] = *(const u16x8*)&attn_b[(size_t)i_ld * N_ + k0 + koff];
    }
    __syncthreads();
    const int fr = lane & 15;
    const int q8 = (lane >> 4) * 8;
    short8 af[4], bf[4];
#pragma unroll
    for (int i = 0; i < 4; ++i) {
      af[i] = *(const short8*)&As[(wm + 16 * i + fr) * 40 + q8];
      bf[i] = *(const short8*)&Bs[(wn + 16 * i + fr) * 40 + q8];
    }
#pragma unroll
    for (int i = 0; i < 4; ++i)
#pragma unroll
      for (int j = 0; j < 4; ++j)
        acc[i][j] = __builtin_amdgcn_mfma_f32_16x16x32_bf16(af[i], bf[j], acc[i][j], 0, 0, 0);
    __syncthreads();
  }
  const float alpha = *alpha_p;
  float* out_b = out + (size_t)b * C_ * N_;
#pragma unroll
  for (int ii = 0; ii < 4; ++ii) {
    const int c = ct * 128 + wm + 16 * ii + ((lane >> 4) * 4);
#pragma unroll
    for (int jj = 0; jj < 4; ++jj) {
      const int i = it * 128 + wn + 16 * jj + (lane & 15);
      if (i < N_) {
#pragma unroll
        for (int r = 0; r < 4; ++r) {
          const size_t off = (size_t)(c + r) * N_ + i;
          out_b[off] = alpha * acc[ii][jj][r] + cam_b[off];
        }
      }
    }
  }
}

// ---------------------------------------------------------------------------
extern "C" void kernel_launch(void* const* d_in, const int* in_sizes, int n_in,
                              void* d_out, int out_size, void* d_ws,
                              size_t ws_size, hipStream_t stream) {
  const float* cam   = (const float*)d_in[0];
  const float* feat  = (const float*)d_in[1];
  const float* W1    = (const float*)d_in[2];
  const float* W2    = (const float*)d_in[3];
  const float* alpha = (const float*)d_in[4];
  float* out = (float*)d_out;

  // ws layout (80.2 MB total, same footprint as the proven R0 layout):
  //   [0, 37.75M)        f12p (packed hi|lo u32) ... later overlaid by attn_bf
  //   [37.75M, 80.22M)   logits fp32 ............. start overlaid by Wh/Wl
  char* ws = (char*)d_ws;
  u32*   f12p    = (u32*)ws;                          // 32*576*512*4
  float* logits  = (float*)(ws + 37748736);           // 32*576*576*4
  u16*   Wh      = (u16*)(ws + 37748736);             // dead before logits written
  u16*   Wl      = Wh + (size_t)M_ * C_;
  u16*   attn_bf = (u16*)ws;                          // overlays f12p (dead then)

  k_prep_w<<<dim3(1024), 256, 0, stream>>>(W1, W2, Wh, Wl);
  k_f12<<<dim3(4, 5, B_), 256, 0, stream>>>(feat, Wh, Wl, f12p);
  k_logits<<<dim3(5, 5, B_), 256, 0, stream>>>(f12p, logits);
  k_softmax<<<dim3(B_ * N_), 64, 0, stream>>>(logits, attn_bf);
  k_out<<<dim3(16, 5, B_), 256, 0, stream>>>(cam, attn_bf, alpha, out);
}